// Round 11
// baseline (1718.241 us; speedup 1.0000x reference)
//
#include <hip/hip_runtime.h>
#include <hip/hip_cooperative_groups.h>
#include <math.h>

namespace cg = cooperative_groups;

#define N_NODES 50000
#define N_EDGES 1200000
#define BATCH   64
#define D       64
#define EPS     1e-12f
#define NCOPY   64
#define PSZ     (NCOPY * BATCH * D)   // floats per pool replica set (1 MB)
#define TPB     512
#define NPAIR   25000
#define NPART   8                     // ticket partitions (contention spread)
#define PPART   (NPAIR / NPART)       // 3125 pairs per partition
#define GRID    1024                  // 4 blocks/CU (40KB LDS) x 256 CUs

// fallback (round-9) grid constants
#define EB  2344
#define MMB 8
#define IB  6258
#define NODE_BLOCKS 3125
#define HSB 4

__device__ __forceinline__ int rfl(int v) { return __builtin_amdgcn_readfirstlane(v); }

// ---------------------------------------------------------------------------
// Shared dense tail: [hA|gA],[hB|gB] @ [M2;M3] + bl, relu, wave l2norm.
// sMM: float4 {M2[2kk][j], M3[2kk][j], M2[2kk+1][j], M3[2kk+1][j]}.
// hg: per-wave 64-entry LDS broadcast region.
// ---------------------------------------------------------------------------
__device__ __forceinline__ void dense2(const float4* __restrict__ sMM,
                                       float4* __restrict__ hg, int l,
                                       float hvA, float hvB, float gvA, float gvB,
                                       float bj, float& oA, float& oB) {
    hg[l] = make_float4(hvA, hvB, gvA, gvB);
    float a2x = 0.f, a2y = 0.f, a3x = bj, a3y = bj;
    #pragma unroll
    for (int kk = 0; kk < 32; ++kk) {
        float4 mm = sMM[kk * 64 + l];
        float4 h0 = hg[2 * kk];
        float4 h1 = hg[2 * kk + 1];
        a2x = fmaf(h0.x, mm.x, a2x); a2y = fmaf(h0.y, mm.x, a2y);
        a3x = fmaf(h0.z, mm.y, a3x); a3y = fmaf(h0.w, mm.y, a3y);
        a2x = fmaf(h1.x, mm.z, a2x); a2y = fmaf(h1.y, mm.z, a2y);
        a3x = fmaf(h1.z, mm.w, a3x); a3y = fmaf(h1.w, mm.w, a3y);
    }
    float vA = fmaxf(a2x + a3x, 0.f);
    float vB = fmaxf(a2y + a3y, 0.f);
    float ssA = vA * vA, ssB = vB * vB;
    #pragma unroll
    for (int off = 32; off; off >>= 1) {
        ssA += __shfl_xor(ssA, off);
        ssB += __shfl_xor(ssB, off);
    }
    oA = vA / fmaxf(sqrtf(ssA), EPS);
    oB = vB / fmaxf(sqrtf(ssB), EPS);
}

// ---------------------------------------------------------------------------
// Persistent cooperative kernel: prologue + 3 iterations + hs updates, one
// dispatch. Node body is the round-9 measured structure (2 rows/wave,
// branch-free 16-deep gather batches, pad-subtract, input-side pooling).
// Pair distribution via 8 partitioned ticket counters (dynamic balance).
// ---------------------------------------------------------------------------
__global__ void __launch_bounds__(TPB, 8) k_all(
    const int* __restrict__ edge_row, const int* __restrict__ edge_col,
    const int* __restrict__ batch,
    const float* __restrict__ X, const float* __restrict__ Xs,
    const float* __restrict__ W1, const float* __restrict__ W2,
    const float* __restrict__ W3, const float* __restrict__ Wl,
    const float* __restrict__ bl,
    float* __restrict__ B0, float* __restrict__ B1,
    float* __restrict__ PA, float* __restrict__ PB,
    int* __restrict__ row_start, unsigned* __restrict__ tickets,
    float* __restrict__ H, float* __restrict__ HS)
{
    cg::grid_group gg = cg::this_grid();
    __shared__ float4 sMM[32 * 64];   // 32 KB fused weights
    __shared__ float4 sHG[8 * 64];    // 8 KB per-wave broadcast
    const int t = threadIdx.x, w = t >> 6, l = t & 63;
    const int bid = blockIdx.x;
    const int gtid = bid * TPB + t;
    const int nthr = gridDim.x * TPB;
    const int gw = bid * 8 + w;
    const int nw = gridDim.x * 8;

    // --- per-block weight fuse straight into LDS (no global round-trip) ---
    {
        float* sf = (float*)sMM;
        for (int i = t; i < D * D; i += TPB) {
            int k = i >> 6, j = i & 63;
            float a2 = 0.f, a3 = 0.f;
            for (int q = 0; q < D; ++q) {
                a2 = fmaf(W2[k * D + q], Wl[q * D + j], a2);
                a3 = fmaf(W3[k * D + q], Wl[(D + q) * D + j], a3);
            }
            sf[(k >> 1) * 256 + j * 4 + (k & 1) * 2 + 0] = a2;
            sf[(k >> 1) * 256 + j * 4 + (k & 1) * 2 + 1] = a3;
        }
    }
    // --- distributed prologue ---
    if (gtid < 3 * NPART) tickets[gtid] = 0u;
    for (int i = gtid; i < 2 * PSZ; i += nthr) PA[i] = 0.f;   // PA||PB contiguous
    for (int i = gtid; i < N_EDGES; i += nthr) {
        int b = edge_row[i];
        int a = (i == 0) ? -1 : edge_row[i - 1];
        for (int r = a + 1; r <= b; ++r) row_start[r] = i;
        if (i == N_EDGES - 1)
            for (int r = b + 1; r <= N_NODES; ++r) row_start[r] = N_EDGES;
    }
    for (int row = gw; row < N_NODES + BATCH; row += nw) {
        float x0, x1; float* out;
        if (row < N_NODES) { x0 = X[row*2]; x1 = X[row*2+1]; out = B0 + (size_t)row * D; }
        else { int r = row - N_NODES; x0 = Xs[r*2]; x1 = Xs[r*2+1]; out = HS + (size_t)r * D; }
        float v = fmaxf(fmaf(x0, W1[l], x1 * W1[D + l]), 0.f);
        float ss = v * v;
        #pragma unroll
        for (int off = 32; off; off >>= 1) ss += __shfl_xor(ss, off);
        out[l] = v / fmaxf(sqrtf(ss), EPS);
    }
    __syncthreads();
    gg.sync();

    float4* hg = &sHG[w * 64];
    const float bj = bl[l];
    const int part = bid & (NPART - 1);

    for (int it = 0; it < 3; ++it) {
        const float* src = (it == 1) ? B1 : B0;
        float* dst = (it == 0) ? B1 : (it == 1) ? B0 : H;
        float* Pw  = (it == 1) ? PB : PA;
        float* cp  = Pw + (size_t)(bid & (NCOPY - 1)) * (BATCH * D);
        unsigned* tk = &tickets[it * NPART + part];
        const float h0l = src[l];

        for (;;) {
            unsigned sub0 = 0;
            if (l == 0) sub0 = atomicAdd(tk, 1u);
            int sub = rfl((int)sub0);
            if (sub >= PPART) break;
            int pr = part * PPART + sub;
            int rA = 2 * pr, rB = rA + 1;
            int sA  = rfl(row_start[rA]);
            int eA  = rfl(row_start[rB]);
            int eB2 = rfl(row_start[rB + 1]);
            float hvA = src[(size_t)rA * D + l];
            float hvB = src[(size_t)rB * D + l];
            float aA = 0.f, aB = 0.f;
            int pad = 0;
            for (int base = sA; base < eB2; ) {
                int cw = eB2 - base; if (cw > 64) cw = 64;
                int col = 0;
                if (l < cw) col = edge_col[base + l];
                int nb = (cw + 15) >> 4;
                pad += (nb << 4) - cw;
                for (int b = 0; b < nb; ++b) {
                    #pragma unroll
                    for (int u = 0; u < 16; ++u) {
                        int idx = (b << 4) + u;
                        int c = __builtin_amdgcn_readlane(col, idx);
                        float v = src[(size_t)c * D + l];   // uniform base -> saddr
                        if (base + idx < eA) aA += v; else aB += v;   // uniform branch
                    }
                }
                base += cw;
            }
            aB -= (float)pad * h0l;
            int bA = rfl(batch[rA]);
            int bB = rfl(batch[rB]);
            atomicAdd(&cp[bA * D + l], hvA);
            atomicAdd(&cp[bB * D + l], hvB);
            float oA, oB;
            dense2(sMM, hg, l, hvA, hvB, aA, aB, bj, oA, oB);
            dst[(size_t)rA * D + l] = oA;
            dst[(size_t)rB * D + l] = oB;
        }
        if (it >= 1 && gw < 32) {   // hs step it: consume pool(h_{it-1}), re-zero it
            float* Pr = (it == 1) ? PA : PB;
            int rA = 2 * gw, rB = rA + 1;
            float hvA = HS[(size_t)rA * D + l];
            float hvB = HS[(size_t)rB * D + l];
            float aA = 0.f, aB = 0.f;
            #pragma unroll 4
            for (int c = 0; c < NCOPY; ++c) {
                float* p = Pr + (size_t)c * (BATCH * D) + rA * D + l;
                float vA = p[0], vB = p[D];
                p[0] = 0.f; p[D] = 0.f;
                aA += vA; aB += vB;
            }
            float oA, oB;
            dense2(sMM, hg, l, hvA, hvB, aA, aB, bj, oA, oB);
            HS[(size_t)rA * D + l] = oA;
            HS[(size_t)rB * D + l] = oB;
        }
        gg.sync();
    }
    if (gw < 32) {   // final hs: consume PA = pool(h2)
        int rA = 2 * gw, rB = rA + 1;
        float hvA = HS[(size_t)rA * D + l];
        float hvB = HS[(size_t)rB * D + l];
        float aA = 0.f, aB = 0.f;
        #pragma unroll 4
        for (int c = 0; c < NCOPY; ++c) {
            const float* p = PA + (size_t)c * (BATCH * D) + rA * D + l;
            aA += p[0]; aB += p[D];
        }
        float oA, oB;
        dense2(sMM, hg, l, hvA, hvB, aA, aB, bj, oA, oB);
        HS[(size_t)rA * D + l] = oA;
        HS[(size_t)rB * D + l] = oB;
    }
}

// ===========================================================================
// Fallback path: round-9 kernels (used only if cooperative launch refuses).
// ===========================================================================
__global__ void __launch_bounds__(512) k_pro(const int* __restrict__ edge_row,
                                             int* __restrict__ row_start,
                                             float* __restrict__ PA, float* __restrict__ PB,
                                             const float* __restrict__ W2,
                                             const float* __restrict__ W3,
                                             const float* __restrict__ Wl,
                                             float* __restrict__ MM4,
                                             const float* __restrict__ X,
                                             const float* __restrict__ Xs,
                                             const float* __restrict__ W1,
                                             float* __restrict__ B0,
                                             float* __restrict__ HS) {
    int bid = blockIdx.x, t = threadIdx.x;
    if (bid < EB) {
        int tid = bid * 512 + t;
        for (int i = tid; i < PSZ; i += EB * 512) { PA[i] = 0.f; PB[i] = 0.f; }
        if (tid < N_EDGES) {
            int b = edge_row[tid];
            int a = (tid == 0) ? -1 : edge_row[tid - 1];
            for (int r = a + 1; r <= b; ++r) row_start[r] = tid;
            if (tid == N_EDGES - 1)
                for (int r = b + 1; r <= N_NODES; ++r) row_start[r] = N_EDGES;
        }
    } else if (bid < EB + MMB) {
        int k = (bid - EB) * 8 + (t >> 6), j = t & 63;
        float a2 = 0.f, a3 = 0.f;
        for (int q = 0; q < D; ++q) {
            a2 += W2[k*D + q] * Wl[q*D + j];
            a3 += W3[k*D + q] * Wl[(D + q)*D + j];
        }
        MM4[(k >> 1) * (D * 4) + j * 4 + (k & 1) * 2 + 0] = a2;
        MM4[(k >> 1) * (D * 4) + j * 4 + (k & 1) * 2 + 1] = a3;
    } else {
        int row = (bid - EB - MMB) * 8 + (t >> 6);
        int j = t & 63;
        if (row >= N_NODES + BATCH) return;
        float x0, x1; float* out;
        if (row < N_NODES) {
            x0 = X[row*2]; x1 = X[row*2 + 1]; out = B0 + (size_t)row * D;
        } else {
            int r = row - N_NODES;
            x0 = Xs[r*2]; x1 = Xs[r*2 + 1]; out = HS + (size_t)r * D;
        }
        float v = fmaxf(fmaf(x0, W1[j], x1 * W1[D + j]), 0.f);
        float ss = v * v;
        #pragma unroll
        for (int off = 32; off; off >>= 1) ss += __shfl_xor(ss, off);
        out[j] = v / fmaxf(sqrtf(ss), EPS);
    }
}

__global__ void __launch_bounds__(512, 8) k_iter(const int* __restrict__ edge_col,
                                                 const int* __restrict__ row_start,
                                                 const float* __restrict__ Hc,
                                                 float* __restrict__ Hn,
                                                 const float* __restrict__ MM4,
                                                 const float* __restrict__ bl,
                                                 const int* __restrict__ batch,
                                                 float* __restrict__ Pout,
                                                 float* __restrict__ HSrw,
                                                 float* __restrict__ Pin,
                                                 int hs_blocks) {
    __shared__ float4 sMM[32 * 64];
    __shared__ float4 sHG[8 * 64];
    int t = threadIdx.x, w = t >> 6, l = t & 63;
    const float4* gMM = (const float4*)MM4;
    for (int i = t; i < 2048; i += 512) sMM[i] = gMM[i];
    __syncthreads();

    int bid = blockIdx.x;
    bool is_hs = (bid < hs_blocks);
    int rA, rB;
    float hvA, hvB, gvA, gvB;

    if (!is_hs) {
        int pr = (bid - hs_blocks) * 8 + w;
        rA = 2 * pr; rB = rA + 1;
        int sA = rfl(row_start[rA]);
        int eA = rfl(row_start[rB]);
        int eB = rfl(row_start[rB + 1]);
        hvA = Hc[(size_t)rA * D + l];
        hvB = Hc[(size_t)rB * D + l];
        float aA = 0.f, aB = 0.f;
        int pad = 0;
        for (int base = sA; base < eB; ) {
            int cw = eB - base; if (cw > 64) cw = 64;
            int col = 0;
            if (l < cw) col = edge_col[base + l];
            int nb = (cw + 15) >> 4;
            pad += (nb << 4) - cw;
            for (int b = 0; b < nb; ++b) {
                #pragma unroll
                for (int u = 0; u < 16; ++u) {
                    int idx = (b << 4) + u;
                    int c = __builtin_amdgcn_readlane(col, idx);
                    float v = Hc[(size_t)c * D + l];
                    if (base + idx < eA) aA += v; else aB += v;
                }
            }
            base += cw;
        }
        aB -= (float)pad * Hc[l];
        gvA = aA; gvB = aB;
        float* cp = Pout + (size_t)(bid & (NCOPY - 1)) * (BATCH * D);
        int bA = rfl(batch[rA]);
        int bB = rfl(batch[rB]);
        atomicAdd(&cp[bA * D + l], hvA);
        atomicAdd(&cp[bB * D + l], hvB);
    } else {
        int pr = bid * 8 + w;
        rA = 2 * pr; rB = rA + 1;
        hvA = HSrw[(size_t)rA * D + l];
        hvB = HSrw[(size_t)rB * D + l];
        float aA = 0.f, aB = 0.f;
        #pragma unroll 4
        for (int c = 0; c < NCOPY; ++c) {
            float* p = Pin + (size_t)c * (BATCH * D) + rA * D + l;
            float vA = p[0], vB = p[D];
            p[0] = 0.f; p[D] = 0.f;
            aA += vA; aB += vB;
        }
        gvA = aA; gvB = aB;
    }

    float oA, oB;
    dense2(sMM, &sHG[w * 64], l, hvA, hvB, gvA, gvB, bl[l], oA, oB);
    float* out = is_hs ? HSrw : Hn;
    out[(size_t)rA * D + l] = oA;
    out[(size_t)rB * D + l] = oB;
}

// ---------------------------------------------------------------------------
extern "C" void kernel_launch(void* const* d_in, const int* in_sizes, int n_in,
                              void* d_out, int out_size, void* d_ws, size_t ws_size,
                              hipStream_t stream) {
    const int*   edge_row = (const int*)  d_in[0];
    const int*   edge_col = (const int*)  d_in[1];
    const int*   batch    = (const int*)  d_in[2];
    const float* X        = (const float*)d_in[3];
    const float* Xs       = (const float*)d_in[4];
    const float* W1       = (const float*)d_in[5];
    const float* W2       = (const float*)d_in[6];
    const float* W3       = (const float*)d_in[7];
    const float* Wl       = (const float*)d_in[8];
    const float* bl       = (const float*)d_in[9];

    float* H  = (float*)d_out;
    float* HS = (float*)d_out + (size_t)N_NODES * D;

    float*    B0        = (float*)d_ws;                     // N_NODES*D
    float*    B1        = B0 + (size_t)N_NODES * D;         // N_NODES*D
    float*    PA        = B1 + (size_t)N_NODES * D;         // PSZ
    float*    PB        = PA + PSZ;                         // PSZ
    float*    MM4       = PB + PSZ;                         // 32*64*4 floats (fallback only)
    int*      row_start = (int*)(MM4 + 32 * 64 * 4);        // N_NODES+1
    unsigned* tickets   = (unsigned*)(row_start + N_NODES + 2); // 3*NPART

    void* args[] = {
        (void*)&edge_row, (void*)&edge_col, (void*)&batch,
        (void*)&X, (void*)&Xs, (void*)&W1, (void*)&W2, (void*)&W3,
        (void*)&Wl, (void*)&bl, (void*)&B0, (void*)&B1,
        (void*)&PA, (void*)&PB, (void*)&row_start, (void*)&tickets,
        (void*)&H, (void*)&HS };

    hipError_t rc = hipLaunchCooperativeKernel((const void*)k_all, dim3(GRID),
                                               dim3(TPB), args, 0, stream);
    if (rc != hipSuccess) {
        // fallback: round-9 multi-dispatch path
        k_pro<<<EB + MMB + IB, 512, 0, stream>>>(edge_row, row_start, PA, PB,
                                                 W2, W3, Wl, MM4, X, Xs, W1, B0, HS);
        k_iter<<<NODE_BLOCKS, 512, 0, stream>>>(edge_col, row_start, B0, B1, MM4, bl,
                                                batch, PA, HS, PA, 0);
        k_iter<<<NODE_BLOCKS + HSB, 512, 0, stream>>>(edge_col, row_start, B1, B0, MM4, bl,
                                                      batch, PB, HS, PA, HSB);
        k_iter<<<NODE_BLOCKS + HSB, 512, 0, stream>>>(edge_col, row_start, B0, H, MM4, bl,
                                                      batch, PA, HS, PB, HSB);
        k_iter<<<HSB, 512, 0, stream>>>(edge_col, row_start, B0, B0, MM4, bl,
                                        batch, PB, HS, PA, HSB);
    }
}

// Round 12
// 498.396 us; speedup vs baseline: 3.4475x; 3.4475x over previous
//
#include <hip/hip_runtime.h>
#include <math.h>

#define N_NODES 50000
#define N_EDGES 1200000
#define BATCH   64
#define D       64
#define EPS     1e-12f
#define NCOPY   64
#define PSZ     (NCOPY * BATCH * D)   // floats per pool replica set (1 MB)

#define EB  2344                      // prologue edge blocks
#define MMB 8                         // prologue weight-fuse blocks
#define IB  6258                      // prologue init blocks (6258*8 = 50064 rows)
#define NB_NODE 768                   // persistent node blocks (3/CU guaranteed)
#define NWAVE   (NB_NODE * 8)         // 6144 node waves
#define NPAIR   25000                 // 4*NWAVE = 24576; waves 0..423 take a 5th pair
#define HSB 4                         // hs blocks: 4 * 8 waves * 2 rows = 64 rows

__device__ __forceinline__ int rfl(int v) { return __builtin_amdgcn_readfirstlane(v); }

__device__ __forceinline__ int pair_of(int gw, int k) {
    return (k < 4) ? (gw + k * NWAVE) : (4 * NWAVE + gw);
}

// ---------------------------------------------------------------------------
// Dense tail: [hA|gA],[hB|gB] @ [M2;M3] + bl, relu, wave l2norm.
// sMM float4 layout: {M2[2kk][j], M3[2kk][j], M2[2kk+1][j], M3[2kk+1][j]}.
// ---------------------------------------------------------------------------
__device__ __forceinline__ void dense2(const float4* __restrict__ sMM,
                                       float4* __restrict__ hg, int l,
                                       float hvA, float hvB, float gvA, float gvB,
                                       float bj, float& oA, float& oB) {
    hg[l] = make_float4(hvA, hvB, gvA, gvB);
    float a2x = 0.f, a2y = 0.f, a3x = bj, a3y = bj;
    #pragma unroll
    for (int kk = 0; kk < 32; ++kk) {
        float4 mm = sMM[kk * 64 + l];
        float4 h0 = hg[2 * kk];
        float4 h1 = hg[2 * kk + 1];
        a2x = fmaf(h0.x, mm.x, a2x); a2y = fmaf(h0.y, mm.x, a2y);
        a3x = fmaf(h0.z, mm.y, a3x); a3y = fmaf(h0.w, mm.y, a3y);
        a2x = fmaf(h1.x, mm.z, a2x); a2y = fmaf(h1.y, mm.z, a2y);
        a3x = fmaf(h1.z, mm.w, a3x); a3y = fmaf(h1.w, mm.w, a3y);
    }
    float vA = fmaxf(a2x + a3x, 0.f);
    float vB = fmaxf(a2y + a3y, 0.f);
    float ssA = vA * vA, ssB = vB * vB;
    #pragma unroll
    for (int off = 32; off; off >>= 1) {
        ssA += __shfl_xor(ssA, off);
        ssB += __shfl_xor(ssB, off);
    }
    oA = vA / fmaxf(sqrtf(ssA), EPS);
    oB = vB / fmaxf(sqrtf(ssB), EPS);
}

// ---------------------------------------------------------------------------
// Prologue: zero 3 pool replica sets, scatter row_start, fuse weights -> MM4,
// init h0 -> B0 and hs0 -> HS.
// ---------------------------------------------------------------------------
__global__ void __launch_bounds__(512) k_pro(const int* __restrict__ edge_row,
                                             int* __restrict__ row_start,
                                             float* __restrict__ PA,
                                             const float* __restrict__ W2,
                                             const float* __restrict__ W3,
                                             const float* __restrict__ Wl,
                                             float* __restrict__ MM4,
                                             const float* __restrict__ X,
                                             const float* __restrict__ Xs,
                                             const float* __restrict__ W1,
                                             float* __restrict__ B0,
                                             float* __restrict__ HS) {
    int bid = blockIdx.x, t = threadIdx.x;
    if (bid < EB) {
        int tid = bid * 512 + t;
        for (int i = tid; i < 3 * PSZ; i += EB * 512) PA[i] = 0.f;  // PA||PB||PC
        if (tid < N_EDGES) {
            int b = edge_row[tid];
            int a = (tid == 0) ? -1 : edge_row[tid - 1];
            for (int r = a + 1; r <= b; ++r) row_start[r] = tid;
            if (tid == N_EDGES - 1)
                for (int r = b + 1; r <= N_NODES; ++r) row_start[r] = N_EDGES;
        }
    } else if (bid < EB + MMB) {
        int k = (bid - EB) * 8 + (t >> 6), j = t & 63;
        float a2 = 0.f, a3 = 0.f;
        for (int q = 0; q < D; ++q) {
            a2 += W2[k*D + q] * Wl[q*D + j];
            a3 += W3[k*D + q] * Wl[(D + q)*D + j];
        }
        MM4[(k >> 1) * (D * 4) + j * 4 + (k & 1) * 2 + 0] = a2;
        MM4[(k >> 1) * (D * 4) + j * 4 + (k & 1) * 2 + 1] = a3;
    } else {
        int row = (bid - EB - MMB) * 8 + (t >> 6);
        int j = t & 63;
        if (row >= N_NODES + BATCH) return;
        float x0, x1; float* out;
        if (row < N_NODES) {
            x0 = X[row*2]; x1 = X[row*2 + 1]; out = B0 + (size_t)row * D;
        } else {
            int r = row - N_NODES;
            x0 = Xs[r*2]; x1 = Xs[r*2 + 1]; out = HS + (size_t)r * D;
        }
        float v = fmaxf(fmaf(x0, W1[j], x1 * W1[D + j]), 0.f);
        float ss = v * v;
        #pragma unroll
        for (int off = 32; off; off >>= 1) ss += __shfl_xor(ss, off);
        out[j] = v / fmaxf(sqrtf(ss), EPS);
    }
}

// ---------------------------------------------------------------------------
// Persistent fused iteration. bid < hs_blocks: hs update chain (Pin1 then
// optionally Pin2, in-register). Other blocks: 8 waves x 4-5 pairs each
// (static stride NWAVE), round-9 branch-free gather preserved verbatim,
// with cross-pair prefetch of row_start/hv/batch (issued before gather) and
// next edge-index vector load (issued before dense). PoolIn: pool input h
// rows; PoolOut: pool output rows.
// ---------------------------------------------------------------------------
__global__ void __launch_bounds__(512, 8) k_iter(const int* __restrict__ edge_col,
                                                 const int* __restrict__ row_start,
                                                 const float* __restrict__ Hc,
                                                 float* __restrict__ Hn,
                                                 const float* __restrict__ MM4,
                                                 const float* __restrict__ bl,
                                                 const int* __restrict__ batch,
                                                 float* __restrict__ PoolIn,
                                                 float* __restrict__ PoolOut,
                                                 float* __restrict__ HSrw,
                                                 const float* __restrict__ Pin1,
                                                 const float* __restrict__ Pin2,
                                                 int hs_blocks) {
    __shared__ float4 sMM[32 * 64];   // 32 KB
    __shared__ float4 sHG[8 * 64];    // 8 KB
    int t = threadIdx.x, w = t >> 6, l = t & 63;
    const float4* gMM = (const float4*)MM4;
    for (int i = t; i < 2048; i += 512) sMM[i] = gMM[i];
    __syncthreads();

    int bid = blockIdx.x;
    float4* hg = &sHG[w * 64];
    const float bj = bl[l];

    if (bid < hs_blocks) {            // ---- hs chain ----
        int gwh = bid * 8 + w;        // 0..31 -> rows 0..63
        int rA = 2 * gwh, rB = rA + 1;
        float hA = HSrw[(size_t)rA * D + l];
        float hB = HSrw[(size_t)rB * D + l];
        if (Pin1) {
            float aA = 0.f, aB = 0.f;
            #pragma unroll 4
            for (int c = 0; c < NCOPY; ++c) {
                const float* p = Pin1 + (size_t)c * (BATCH * D) + rA * D + l;
                aA += p[0]; aB += p[D];
            }
            float oA, oB;
            dense2(sMM, hg, l, hA, hB, aA, aB, bj, oA, oB);
            hA = oA; hB = oB;
        }
        if (Pin2) {
            float aA = 0.f, aB = 0.f;
            #pragma unroll 4
            for (int c = 0; c < NCOPY; ++c) {
                const float* p = Pin2 + (size_t)c * (BATCH * D) + rA * D + l;
                aA += p[0]; aB += p[D];
            }
            float oA, oB;
            dense2(sMM, hg, l, hA, hB, aA, aB, bj, oA, oB);
            hA = oA; hB = oB;
        }
        HSrw[(size_t)rA * D + l] = hA;
        HSrw[(size_t)rB * D + l] = hB;
        return;
    }

    // ---- node path: persistent, 4-5 pairs per wave, prefetched ----
    const int gw = (bid - hs_blocks) * 8 + w;
    const int npw = 4 + ((gw < NPAIR - 4 * NWAVE) ? 1 : 0);
    const bool pool = (PoolIn != nullptr) || (PoolOut != nullptr);
    const float h0l = Hc[l];          // row 0 (pad lanes gather row 0)

    // prologue: pair 0 state
    int p = gw;
    int rs0 = row_start[2*p], rs1 = row_start[2*p+1], rs2 = row_start[2*p+2];
    float hvA = Hc[(size_t)(2*p) * D + l];
    float hvB = Hc[(size_t)(2*p) * D + D + l];
    int bA = 0, bB = 0;
    if (pool) { bA = batch[2*p]; bB = batch[2*p+1]; }
    int sA = rfl(rs0), eA = rfl(rs1), eB2 = rfl(rs2);
    int colv = 0;
    { int ei = sA + l; if (ei < N_EDGES) colv = edge_col[ei]; }

    for (int k = 0; k < npw; ++k) {
        // issue next-pair row_start / hv / batch loads (hidden under gather)
        const bool hasnext = (k + 1 < npw);
        int pn = p, rs0n = 0, rs1n = 0, rs2n = 0, bAn = 0, bBn = 0;
        float hvAn = 0.f, hvBn = 0.f;
        if (hasnext) {
            pn = pair_of(gw, k + 1);
            rs0n = row_start[2*pn]; rs1n = row_start[2*pn+1]; rs2n = row_start[2*pn+2];
            hvAn = Hc[(size_t)(2*pn) * D + l];
            hvBn = Hc[(size_t)(2*pn) * D + D + l];
            if (pool) { bAn = batch[2*pn]; bBn = batch[2*pn+1]; }
        }
        // gather current pair (round-9 branch-free structure)
        float aA = 0.f, aB = 0.f;
        int pad = 0;
        int cv = colv;
        for (int base = sA; base < eB2; ) {
            int cw = eB2 - base; if (cw > 64) cw = 64;
            int col = (l < cw) ? cv : 0;
            int nb = (cw + 15) >> 4;
            pad += (nb << 4) - cw;
            for (int b = 0; b < nb; ++b) {
                #pragma unroll
                for (int u = 0; u < 16; ++u) {
                    int idx = (b << 4) + u;
                    int c = __builtin_amdgcn_readlane(col, idx);
                    float v = Hc[(size_t)c * D + l];   // uniform base -> saddr
                    if (base + idx < eA) aA += v; else aB += v;   // uniform branch
                }
            }
            base += cw;
            if (base < eB2) {   // rare extra chunk (>64 edges/pair): inline load
                int ei = base + l;
                cv = (ei < N_EDGES) ? edge_col[ei] : 0;
            }
        }
        aB -= (float)pad * h0l;

        // issue next-pair edge-index vector load (hidden under dense phase)
        int sAn = 0, eAn = 0, eB2n = 0, colvn = 0;
        if (hasnext) {
            sAn = rfl(rs0n); eAn = rfl(rs1n); eB2n = rfl(rs2n);
            int ei = sAn + l;
            if (ei < N_EDGES) colvn = edge_col[ei];
        }

        int rA = 2 * p, rB = rA + 1;
        if (PoolIn) {
            float* cp = PoolIn + (size_t)(bid & (NCOPY - 1)) * (BATCH * D);
            atomicAdd(&cp[rfl(bA) * D + l], hvA);
            atomicAdd(&cp[rfl(bB) * D + l], hvB);
        }
        float oA, oB;
        dense2(sMM, hg, l, hvA, hvB, aA, aB, bj, oA, oB);
        Hn[(size_t)rA * D + l] = oA;
        Hn[(size_t)rB * D + l] = oB;
        if (PoolOut) {
            float* cp = PoolOut + (size_t)(bid & (NCOPY - 1)) * (BATCH * D);
            atomicAdd(&cp[rfl(bA) * D + l], oA);
            atomicAdd(&cp[rfl(bB) * D + l], oB);
        }
        // rotate pipeline registers
        p = pn; sA = sAn; eA = eAn; eB2 = eB2n; colv = colvn;
        hvA = hvAn; hvB = hvBn; bA = bAn; bB = bBn;
    }
}

// ---------------------------------------------------------------------------
extern "C" void kernel_launch(void* const* d_in, const int* in_sizes, int n_in,
                              void* d_out, int out_size, void* d_ws, size_t ws_size,
                              hipStream_t stream) {
    const int*   edge_row = (const int*)  d_in[0];
    const int*   edge_col = (const int*)  d_in[1];
    const int*   batch    = (const int*)  d_in[2];
    const float* X        = (const float*)d_in[3];
    const float* Xs       = (const float*)d_in[4];
    const float* W1       = (const float*)d_in[5];
    const float* W2       = (const float*)d_in[6];
    const float* W3       = (const float*)d_in[7];
    const float* Wl       = (const float*)d_in[8];
    const float* bl       = (const float*)d_in[9];

    float* H  = (float*)d_out;                        // final node embeddings
    float* HS = (float*)d_out + (size_t)N_NODES * D;  // hs (updated in place)

    float* B0  = (float*)d_ws;                          // N_NODES*D
    float* B1  = B0 + (size_t)N_NODES * D;              // N_NODES*D
    float* PA  = B1 + (size_t)N_NODES * D;              // PSZ  (pool h0)
    float* PB  = PA + PSZ;                              // PSZ  (pool h1)
    float* PC  = PB + PSZ;                              // PSZ  (pool h2)
    float* MM4 = PC + PSZ;                              // 32*64*4 floats
    int*   row_start = (int*)(MM4 + 32 * 64 * 4);       // N_NODES+1

    // prologue: pools zeroed, row_start scattered, MM4 fused, h0/hs0 init
    k_pro<<<EB + MMB + IB, 512, 0, stream>>>(edge_row, row_start, PA,
                                             W2, W3, Wl, MM4, X, Xs, W1, B0, HS);

    // iter 1: h0(B0)->h1(B1); pool input h0->PA, output h1->PB ; no hs
    k_iter<<<NB_NODE, 512, 0, stream>>>(edge_col, row_start, B0, B1, MM4, bl,
                                        batch, PA, PB, HS, nullptr, nullptr, 0);
    // iter 2: h1(B1)->h2(B0); pool output h2->PC ; hs chain: hs1(PA), hs2(PB)
    k_iter<<<NB_NODE + HSB, 512, 0, stream>>>(edge_col, row_start, B1, B0, MM4, bl,
                                              batch, nullptr, PC, HS, PA, PB, HSB);
    // iter 3: h2(B0)->h3(H); no pooling ; hs: hs3(PC)
    k_iter<<<NB_NODE + HSB, 512, 0, stream>>>(edge_col, row_start, B0, H, MM4, bl,
                                              batch, nullptr, nullptr, HS, PC, nullptr, HSB);
}